// Round 20
// baseline (42.538 us; speedup 1.0000x reference)
//
#include <hip/hip_runtime.h>

// STN forward, R20: max-TLP, tile 4x4x16, 1 voxel/thread, NT=256.
// LDS 16,384B/block -> 8 blocks/CU (waves-capped), up from ~4 at R19's
// 20.5KB. Row = 28 dwords => bank offset 28*row mod 32 cycles through 8
// DISTINCT offsets (R19's 40-dword rows aliased every 4 rows). Staging =
// exactly 4 uniform global_load_lds rounds (1024 granules; rows >120
// clamp-duplicate, never read). Coords/weights/addr computed once,
// persisted across both channel passes. Scalar IO = 4 full 64B segments
// per wave (16 consecutive w per h-row) -> no partial-line waste.

constexpr int B = 2, C = 2, D = 128, H = 128, W = 128;
constexpr int HW  = H * W;
constexpr int DHW = D * HW;
constexpr int RDH = 11;                      // d,h region extents (halo 3)
constexpr int ROWD = 28;                     // LDS row dwords (w: 24 used + 4 pad)
constexpr int NROWR = 121;                   // real rows
constexpr int GPR = 7;                       // granules per row
constexpr int NG = 1024;                     // staged granules = 4 * 256
constexpr int NT = 256;
constexpr int ROW_B = ROWD * 4;              // 112 B
constexpr int PLANE_B = RDH * ROW_B;         // 1232 B

typedef float v2f __attribute__((ext_vector_type(2)));

__device__ __forceinline__ void gload_lds16(const float* g, float* l) {
    __builtin_amdgcn_global_load_lds(
        (const __attribute__((address_space(1))) void*)g,
        (__attribute__((address_space(3))) void*)l, 16, 0, 0);
}

__global__ __launch_bounds__(NT) void stn_kernel(
    const float* __restrict__ image,
    const float* __restrict__ ddf,
    float* __restrict__ out)
{
    __shared__ float smem[NG * 4];           // 16,384 B

    // XCD-contiguous swizzle (16384 blocks, %8==0 -> bijective)
    const int bid = blockIdx.x;
    const int cpx = gridDim.x >> 3;          // 2048
    const int blk = (bid & 7) * cpx + (bid >> 3);

    const int b  = blk >> 13;                // 8192 tiles/batch: 32d x 32h x 8w
    const int tb = blk & 8191;
    const int t0d = (tb >> 8) * 4;
    const int t0h = ((tb >> 3) & 31) * 4;
    const int t0w = (tb & 7) * 16;
    const int lo_d = max(t0d - 3, 0), lo_h = max(t0h - 3, 0);
    const int lo_w = max(t0w - 4, 0);        // 4-aligned
    const int hi_d = min(lo_d + RDH - 1, D - 1);
    const int hi_h = min(lo_h + RDH - 1, H - 1);
    const int hi_w = min(lo_w + 23, W - 1);  // cols 0..23 valid (24..27 pad)
    const float* imgb = image + (size_t)b * C * DHW;
    const int tid = threadIdx.x;
    const unsigned lds0 =
        (unsigned)(uintptr_t)(__attribute__((address_space(3))) void*)&smem[0];

    // 1 voxel/thread
    const int dd = tid >> 6, hh = (tid >> 4) & 3, wl = tid & 15;
    const int d_ = t0d + dd, h_ = t0h + hh, w_ = t0w + wl;
    const int sidx = d_ * HW + h_ * W + w_;

    // ---- ddf loads FIRST ----
    const float* dp = ddf + (size_t)b * 3 * DHW;
    float vdd = dp[sidx];
    float vhh = dp[DHW + sidx];
    float vww = dp[2 * DHW + sidx];
    asm volatile("" ::: "memory");

    // granule g -> global offset (rows >120 clamp-duplicate; w-overhang clamps
    // to W-4 only in the never-read pad/edge cols)
    auto gsrc_off = [&](int g) {
        int row = g / GPR;
        int rw  = (g - row * GPR) * 4;
        int rc  = min(row, NROWR - 1);
        int rd  = rc / RDH;
        int rh  = rc - rd * RDH;
        return min(lo_d + rd, D - 1) * HW + min(lo_h + rh, H - 1) * W
             + min(lo_w + rw, W - 4);
    };

    auto issue_stage = [&](const float* src) {
#pragma unroll
        for (int i = 0; i < 4; ++i) {        // exactly 4 rounds, no tail
            int g = tid + i * NT;
            gload_lds16(src + gsrc_off(g), &smem[g * 4]);
        }
    };

    issue_stage(imgb);                       // ch0 in flight
    asm volatile("" ::: "memory");

    // coords/weights/addr computed ONCE (persisted across both passes)
    float cd = fminf(fmaxf((float)d_ + vdd, 0.0f), (float)(D - 1));
    float ch = fminf(fmaxf((float)h_ + vhh, 0.0f), (float)(H - 1));
    float cw = fminf(fmaxf((float)w_ + vww, 0.0f), (float)(W - 1));
    float d0f = floorf(cd), h0f = floorf(ch), w0f = floorf(cw);
    float FD = cd - d0f, FH = ch - h0f, FW = cw - w0f;
    float GD = 1.0f - FD, GHt = 1.0f - FH, GWt = 1.0f - FW;
    int d0 = (int)d0f, h0 = (int)h0f, w0 = (int)w0f;
    const bool bad = (d0 < lo_d) | (d0 + 1 > hi_d)
                   | (h0 < lo_h) | (h0 + 1 > hi_h)
                   | (w0 < lo_w) | (w0 + 1 > hi_w);
    float W00 = GHt * GWt, W01 = GHt * FW, W10 = FH * GWt, W11 = FH * FW;
    const unsigned a0 = lds0 +
        (unsigned)(((d0 - lo_d) * RDH + (h0 - lo_h)) * ROW_B + (w0 - lo_w) * 4);
    const unsigned a1 = a0 + PLANE_B;

    // one pass: 4 ds_read2_b32 batched -> one wait -> FMAs; rare fixup; store
    auto do_pass = [&](const float* gimg, float* optr) {
        v2f r00, r01, r10, r11;
        asm volatile("ds_read2_b32 %0, %1 offset0:0 offset1:1"
                     : "=v"(r00) : "v"(a0));
        asm volatile("ds_read2_b32 %0, %1 offset0:28 offset1:29"
                     : "=v"(r01) : "v"(a0));
        asm volatile("ds_read2_b32 %0, %1 offset0:0 offset1:1"
                     : "=v"(r10) : "v"(a1));
        asm volatile("ds_read2_b32 %0, %1 offset0:28 offset1:29"
                     : "=v"(r11) : "v"(a1));
        asm volatile("s_waitcnt lgkmcnt(0)" ::: "memory");
        __builtin_amdgcn_sched_barrier(0);

        float p0 = r00.x * W00 + r00.y * W01 + r01.x * W10 + r01.y * W11;
        float p1 = r10.x * W00 + r10.y * W01 + r11.x * W10 + r11.y * W11;
        float acc = GD * p0 + FD * p1;

        if (bad) {                           // rare: exact global recompute
            int d1i = min(d0 + 1, D - 1);
            int h1i = min(h0 + 1, H - 1);
            int w1i = min(w0 + 1, W - 1);
            int o00 = d0 * HW + h0 * W, o01 = d0 * HW + h1i * W;
            int o10 = d1i * HW + h0 * W, o11 = d1i * HW + h1i * W;
            float q0 = gimg[o00 + w0] * W00 + gimg[o00 + w1i] * W01
                     + gimg[o01 + w0] * W10 + gimg[o01 + w1i] * W11;
            float q1 = gimg[o10 + w0] * W00 + gimg[o10 + w1i] * W01
                     + gimg[o11 + w0] * W10 + gimg[o11 + w1i] * W11;
            acc = GD * q0 + FD * q1;
        }
        *optr = acc;
    };

    float* outb = out + (size_t)b * C * DHW;

    // ---- pass 0 ----
    asm volatile("s_waitcnt vmcnt(0)" ::: "memory");    // ch0 staged
    __builtin_amdgcn_s_barrier();
    do_pass(imgb, outb + sidx);

    __builtin_amdgcn_s_barrier();                       // ch0 reads done
    asm volatile("" ::: "memory");

    // ---- pass 1 ----
    issue_stage(imgb + DHW);
    asm volatile("s_waitcnt vmcnt(0)" ::: "memory");    // ch1 staged
    __builtin_amdgcn_s_barrier();
    do_pass(imgb + DHW, outb + DHW + sidx);
}

extern "C" void kernel_launch(void* const* d_in, const int* in_sizes, int n_in,
                              void* d_out, int out_size, void* d_ws, size_t ws_size,
                              hipStream_t stream) {
    const float* image = (const float*)d_in[0];
    const float* ddf   = (const float*)d_in[1];
    float* out = (float*)d_out;

    int grid = B * 8192;   // 32d x 32h x 8w tiles of 4x4x16 = 16384 blocks
    stn_kernel<<<grid, NT, 0, stream>>>(image, ddf, out);
}

// Round 21
// 35.299 us; speedup vs baseline: 1.2051x; 1.2051x over previous
//
#include <hip/hip_runtime.h>

// STN forward, R21: tuned R19. Tile 4x8x32 (d,h,w), NT=512, 2 vox/thread.
// Staged region 11x15x40 -> 6.4 floats/voxel amplification (R19: 9.45,
// R20: 12.8 - work increase beat TLP there). LDS rows padded to 44 dwords
// (bank offset 12/row, aliases every 8 rows vs R19's every 4) = 32,768B
// -> 4 blocks/CU = 32 waves (nominal max). 4096 blocks keep cross-block
// stagger (the R19 lever). Two single-channel passes over one buffer;
// uniform global_load_lds staging (4 rounds x 512, clamp-dup never read);
// gather = 4x ds_read2_b32 per voxel, batched, one lgkmcnt+sched_barrier.

constexpr int B = 2, C = 2, D = 128, H = 128, W = 128;
constexpr int HW  = H * W;
constexpr int DHW = D * HW;
constexpr int RD = 11, RH = 15;              // region extents (halo 3)
constexpr int ROWD = 44;                     // LDS row dwords (40 used + 4 pad)
constexpr int GPR = 11;                      // granules per row
constexpr int NROWR = RD * RH;               // 165 real rows
constexpr int NG = 2048;                     // staged granules = 4 * 512
constexpr int NT = 512;
constexpr int ROW_B = ROWD * 4;              // 176 B
constexpr int PLANE_B = RH * ROW_B;          // 2640 B

typedef float v2f __attribute__((ext_vector_type(2)));

__device__ __forceinline__ void gload_lds16(const float* g, float* l) {
    __builtin_amdgcn_global_load_lds(
        (const __attribute__((address_space(1))) void*)g,
        (__attribute__((address_space(3))) void*)l, 16, 0, 0);
}

__global__ __launch_bounds__(NT) void stn_kernel(
    const float* __restrict__ image,
    const float* __restrict__ ddf,
    float* __restrict__ out)
{
    __shared__ float smem[NG * 4];           // 32,768 B

    // XCD-contiguous swizzle (4096 blocks, %8==0 -> bijective)
    const int bid = blockIdx.x;
    const int cpx = gridDim.x >> 3;          // 512
    const int blk = (bid & 7) * cpx + (bid >> 3);

    const int b  = blk >> 11;                // 2048 tiles/batch: 32d x 16h x 4w
    const int tb = blk & 2047;
    const int t0d = (tb >> 6) * 4;
    const int t0h = ((tb >> 2) & 15) * 8;
    const int t0w = (tb & 3) * 32;
    const int lo_d = max(t0d - 3, 0), lo_h = max(t0h - 3, 0);
    const int lo_w = max(t0w - 4, 0);        // 4-aligned
    const int hi_d = min(lo_d + RD - 1, D - 1);
    const int hi_h = min(lo_h + RH - 1, H - 1);
    const int hi_w = min(lo_w + 39, W - 1);  // cols 40..43 are pad
    const float* imgb = image + (size_t)b * C * DHW;
    const int tid = threadIdx.x;
    const unsigned lds0 =
        (unsigned)(uintptr_t)(__attribute__((address_space(3))) void*)&smem[0];

    // 2 voxels/thread: (d_, h_, w2) and (d_, h_, w2+1)
    const int dd = tid >> 7, hh = (tid >> 4) & 7, wi = tid & 15;
    const int d_ = t0d + dd, h_ = t0h + hh;
    const int w2 = t0w + wi * 2;
    const int sidx = d_ * HW + h_ * W + w2;

    // ---- ddf loads FIRST ----
    const float* dp = ddf + (size_t)b * 3 * DHW;
    float2 vd = *reinterpret_cast<const float2*>(dp + sidx);
    float2 vh = *reinterpret_cast<const float2*>(dp + DHW + sidx);
    float2 vw = *reinterpret_cast<const float2*>(dp + 2 * DHW + sidx);
    asm volatile("" ::: "memory");

    // granule g -> global offset (rows >164 and w/h/d overhang clamp-duplicate,
    // provably outside the read index range)
    auto gsrc_off = [&](int g) {
        int row = g / GPR;
        int rw  = (g - row * GPR) * 4;
        int rc  = min(row, NROWR - 1);
        int rd  = rc / RH;
        int rh  = rc - rd * RH;
        return min(lo_d + rd, D - 1) * HW + min(lo_h + rh, H - 1) * W
             + min(lo_w + rw, W - 4);
    };

    auto issue_stage = [&](const float* src) {
#pragma unroll
        for (int i = 0; i < 4; ++i) {        // exactly 4 rounds, no tail
            int g = tid + i * NT;
            gload_lds16(src + gsrc_off(g), &smem[g * 4]);
        }
    };

    issue_stage(imgb);                       // ch0 in flight
    asm volatile("" ::: "memory");

    // clamped coords (persisted across both passes; 6 VGPR)
    float cds[2], chs[2], cws[2];
    cds[0] = fminf(fmaxf((float)d_ + vd.x, 0.0f), (float)(D - 1));
    cds[1] = fminf(fmaxf((float)d_ + vd.y, 0.0f), (float)(D - 1));
    chs[0] = fminf(fmaxf((float)h_ + vh.x, 0.0f), (float)(H - 1));
    chs[1] = fminf(fmaxf((float)h_ + vh.y, 0.0f), (float)(H - 1));
    cws[0] = fminf(fmaxf((float)w2 + vw.x, 0.0f), (float)(W - 1));
    cws[1] = fminf(fmaxf((float)(w2 + 1) + vw.y, 0.0f), (float)(W - 1));

    // weights/addresses computed once (persisted across both passes)
    unsigned a0[2];
    float W00[2], W01[2], W10[2], W11[2], GD[2], FD[2];
    int fb = 0;
#pragma unroll
    for (int k = 0; k < 2; ++k) {
        float cd = cds[k], ch = chs[k], cw = cws[k];
        float d0f = floorf(cd), h0f = floorf(ch), w0f = floorf(cw);
        float fd = cd - d0f, fh = ch - h0f, fw = cw - w0f;
        int d0 = (int)d0f, h0 = (int)h0f, w0 = (int)w0f;
        bool bad = (d0 < lo_d) | (d0 + 1 > hi_d)
                 | (h0 < lo_h) | (h0 + 1 > hi_h)
                 | (w0 < lo_w) | (w0 + 1 > hi_w);
        fb |= (int)bad << k;
        float gh = 1.0f - fh, gw = 1.0f - fw;
        W00[k] = gh * gw; W01[k] = gh * fw;
        W10[k] = fh * gw; W11[k] = fh * fw;
        GD[k] = 1.0f - fd; FD[k] = fd;
        int row = (d0 - lo_d) * RH + (h0 - lo_h);
        a0[k] = lds0 + (unsigned)(row * ROW_B + (w0 - lo_w) * 4);
    }

    // one pass: 8 ds_read2_b32 batched -> one wait -> FMAs; rare fixup; store
    auto do_pass = [&](const float* gimg, float* optr) {
        v2f r00[2], r01[2], r10[2], r11[2];
#pragma unroll
        for (int k = 0; k < 2; ++k) {
            unsigned a1 = a0[k] + PLANE_B;
            asm volatile("ds_read2_b32 %0, %1 offset0:0 offset1:1"
                         : "=v"(r00[k]) : "v"(a0[k]));
            asm volatile("ds_read2_b32 %0, %1 offset0:44 offset1:45"
                         : "=v"(r01[k]) : "v"(a0[k]));
            asm volatile("ds_read2_b32 %0, %1 offset0:0 offset1:1"
                         : "=v"(r10[k]) : "v"(a1));
            asm volatile("ds_read2_b32 %0, %1 offset0:44 offset1:45"
                         : "=v"(r11[k]) : "v"(a1));
        }
        asm volatile("s_waitcnt lgkmcnt(0)" ::: "memory");
        __builtin_amdgcn_sched_barrier(0);

        float acc[2];
#pragma unroll
        for (int k = 0; k < 2; ++k) {
            float p0 = r00[k].x * W00[k] + r00[k].y * W01[k]
                     + r01[k].x * W10[k] + r01[k].y * W11[k];
            float p1 = r10[k].x * W00[k] + r10[k].y * W01[k]
                     + r11[k].x * W10[k] + r11[k].y * W11[k];
            acc[k] = GD[k] * p0 + FD[k] * p1;
        }
        if (fb) {                            // rare: exact global recompute
#pragma unroll
            for (int k = 0; k < 2; ++k) {
                if (fb & (1 << k)) {
                    float cd = cds[k], ch = chs[k], cw = cws[k];
                    float d0f = floorf(cd), h0f = floorf(ch), w0f = floorf(cw);
                    float fd = cd - d0f, fh = ch - h0f, fw = cw - w0f;
                    int d0 = (int)d0f, h0 = (int)h0f, w0 = (int)w0f;
                    int d1 = min(d0 + 1, D - 1);
                    int h1 = min(h0 + 1, H - 1);
                    int w1 = min(w0 + 1, W - 1);
                    float gd = 1.0f - fd, gh = 1.0f - fh, gw = 1.0f - fw;
                    float w00 = gh * gw, w01 = gh * fw, w10 = fh * gw, w11 = fh * fw;
                    int o00 = d0 * HW + h0 * W, o01 = d0 * HW + h1 * W;
                    int o10 = d1 * HW + h0 * W, o11 = d1 * HW + h1 * W;
                    float q0 = gimg[o00 + w0] * w00 + gimg[o00 + w1] * w01
                             + gimg[o01 + w0] * w10 + gimg[o01 + w1] * w11;
                    float q1 = gimg[o10 + w0] * w00 + gimg[o10 + w1] * w01
                             + gimg[o11 + w0] * w10 + gimg[o11 + w1] * w11;
                    acc[k] = gd * q0 + fd * q1;
                }
            }
        }
        *reinterpret_cast<float2*>(optr) = make_float2(acc[0], acc[1]);
    };

    float* outb = out + (size_t)b * C * DHW;

    // ---- pass 0 ----
    asm volatile("s_waitcnt vmcnt(0)" ::: "memory");    // ch0 staged
    __builtin_amdgcn_s_barrier();
    do_pass(imgb, outb + sidx);

    __builtin_amdgcn_s_barrier();                       // ch0 reads done
    asm volatile("" ::: "memory");

    // ---- pass 1 ----
    issue_stage(imgb + DHW);
    asm volatile("s_waitcnt vmcnt(0)" ::: "memory");    // ch1 staged
    __builtin_amdgcn_s_barrier();
    do_pass(imgb + DHW, outb + DHW + sidx);
}

extern "C" void kernel_launch(void* const* d_in, const int* in_sizes, int n_in,
                              void* d_out, int out_size, void* d_ws, size_t ws_size,
                              hipStream_t stream) {
    const float* image = (const float*)d_in[0];
    const float* ddf   = (const float*)d_in[1];
    float* out = (float*)d_out;

    int grid = B * 2048;   // 32d x 16h x 4w tiles of 4x8x32 = 4096 blocks
    stn_kernel<<<grid, NT, 0, stream>>>(image, ddf, out);
}